// Round 1
// baseline (2709.509 us; speedup 1.0000x reference)
//
#include <hip/hip_runtime.h>

#define D 64

// ---------------------------------------------------------------------------
// Detect whether edge_index is stored as int64 (odd int32 words all zero)
// or int32. Writes 1 (int64) / 0 (int32) to *flag.
// ---------------------------------------------------------------------------
__global__ void detect_kernel(const void* __restrict__ e, int* __restrict__ flag) {
    if (threadIdx.x == 0 && blockIdx.x == 0) {
        const int* p = (const int*)e;
        int is64 = 1;
        for (int i = 1; i < 64; i += 2) {
            if (p[i] != 0) { is64 = 0; break; }
        }
        *flag = is64;
    }
}

// ---------------------------------------------------------------------------
// Scatter-add: aggr[dst] += feat[src] for every edge.
// 16 threads per edge, each handling a float4 chunk (4 hw f32 atomics).
// ---------------------------------------------------------------------------
__global__ __launch_bounds__(256) void scatter_kernel(
    const float* __restrict__ feat, const void* __restrict__ eidx,
    const int* __restrict__ flag, float* __restrict__ aggr, int nE)
{
    const int is64 = *flag;
    long long t = (long long)blockIdx.x * 256 + threadIdx.x;
    long long nwork = (long long)nE * 16;
    if (t >= nwork) return;
    long long e = t >> 4;
    int c = (int)(t & 15);
    long long src, dst;
    if (is64) {
        const long long* p = (const long long*)eidx;
        src = p[e];
        dst = p[nE + e];
    } else {
        const int* p = (const int*)eidx;
        src = p[e];
        dst = p[nE + e];
    }
    float4 v = *(const float4*)(feat + src * D + c * 4);
    float* d = aggr + dst * D + c * 4;
    unsafeAtomicAdd(d + 0, v.x);
    unsafeAtomicAdd(d + 1, v.y);
    unsafeAtomicAdd(d + 2, v.z);
    unsafeAtomicAdd(d + 3, v.w);
}

// ---------------------------------------------------------------------------
// Fused linear: out[i][d] = relu( sum_k aggr[i][k]*Wrel[k][d]
//                                + sum_k  in[i][k]*Wroot[k][d] + b[d] )
// One wave per row; lane d holds columns d of both weights in registers.
// Optionally accumulates per-block column sums (for the final mean).
// ---------------------------------------------------------------------------
template <bool WRITE_OUT, bool WRITE_PART>
__global__ __launch_bounds__(256) void linear_relu_kernel(
    const float* __restrict__ in, const float* __restrict__ aggr,
    const float* __restrict__ Wrel, const float* __restrict__ Wroot,
    const float* __restrict__ bias,
    float* __restrict__ out, float* __restrict__ part, int N)
{
    const int lane = threadIdx.x & 63;
    const int wid  = threadIdx.x >> 6;

    float wrel[D], wroot[D];
#pragma unroll
    for (int k = 0; k < D; ++k) {
        wrel[k]  = Wrel[k * D + lane];
        wroot[k] = Wroot[k * D + lane];
    }
    const float bv = bias[lane];

    float csum = 0.f;
    const long long stride = (long long)gridDim.x * 4;
    for (long long row = (long long)blockIdx.x * 4 + wid; row < N; row += stride) {
        const float* rin = in   + row * D;
        const float* rag = aggr + row * D;
        float acc = bv;
#pragma unroll
        for (int k4 = 0; k4 < D / 4; ++k4) {
            float4 a = *(const float4*)(rin + 4 * k4);
            float4 g = *(const float4*)(rag + 4 * k4);
            acc += a.x * wroot[4 * k4 + 0] + a.y * wroot[4 * k4 + 1]
                 + a.z * wroot[4 * k4 + 2] + a.w * wroot[4 * k4 + 3];
            acc += g.x * wrel[4 * k4 + 0] + g.y * wrel[4 * k4 + 1]
                 + g.z * wrel[4 * k4 + 2] + g.w * wrel[4 * k4 + 3];
        }
        acc = fmaxf(acc, 0.f);
        if (WRITE_OUT) out[row * D + lane] = acc;
        if (WRITE_PART) csum += acc;
    }

    if (WRITE_PART) {
        __shared__ float red[4][D];
        red[wid][lane] = csum;
        __syncthreads();
        if (threadIdx.x < D) {
            float s = red[0][threadIdx.x] + red[1][threadIdx.x]
                    + red[2][threadIdx.x] + red[3][threadIdx.x];
            part[(long long)blockIdx.x * D + threadIdx.x] = s;
        }
    }
}

// ---------------------------------------------------------------------------
// Final: colsum -> mean -> [64] @ Wc[64,2] + bc -> out[2]
// ---------------------------------------------------------------------------
__global__ void final_kernel(const float* __restrict__ part, int nPart,
                             const float* __restrict__ Wc, const float* __restrict__ bc,
                             float* __restrict__ out, float invN)
{
    const int lane = threadIdx.x;  // 64 threads
    float s = 0.f;
    for (int b = 0; b < nPart; ++b) s += part[(long long)b * D + lane];
    float m  = s * invN;
    float o0 = m * Wc[lane * 2 + 0];
    float o1 = m * Wc[lane * 2 + 1];
#pragma unroll
    for (int off = 32; off > 0; off >>= 1) {
        o0 += __shfl_down(o0, off);
        o1 += __shfl_down(o1, off);
    }
    if (lane == 0) {
        out[0] = o0 + bc[0];
        out[1] = o1 + bc[1];
    }
}

extern "C" void kernel_launch(void* const* d_in, const int* in_sizes, int n_in,
                              void* d_out, int out_size, void* d_ws, size_t ws_size,
                              hipStream_t stream)
{
    const float* x       = (const float*)d_in[0];
    const void*  eidx    = d_in[1];
    const float* W1_rel  = (const float*)d_in[2];
    const float* W1_root = (const float*)d_in[3];
    const float* b1      = (const float*)d_in[4];
    const float* W2_rel  = (const float*)d_in[5];
    const float* W2_root = (const float*)d_in[6];
    const float* b2      = (const float*)d_in[7];
    const float* Wc      = (const float*)d_in[8];
    const float* bc      = (const float*)d_in[9];
    float* out = (float*)d_out;

    const int N = in_sizes[0] / D;
    const int E = in_sizes[1] / 2;

    char* ws = (char*)d_ws;
    const size_t featBytes = (size_t)N * D * sizeof(float);
    const int GRID2 = 1024;
    float* aggr = (float*)ws;
    float* h1   = (float*)(ws + featBytes);
    float* part = (float*)(ws + 2 * featBytes);
    int*   flag = (int*)  (ws + 2 * featBytes + (size_t)GRID2 * D * sizeof(float));

    detect_kernel<<<1, 64, 0, stream>>>(eidx, flag);

    const long long nwork = (long long)E * 16;
    const int sblocks = (int)((nwork + 255) / 256);

    // ---- layer 1 ----
    hipMemsetAsync(aggr, 0, featBytes, stream);
    scatter_kernel<<<sblocks, 256, 0, stream>>>(x, eidx, flag, aggr, E);
    linear_relu_kernel<true, false><<<2048, 256, 0, stream>>>(
        x, aggr, W1_rel, W1_root, b1, h1, nullptr, N);

    // ---- layer 2 ----
    hipMemsetAsync(aggr, 0, featBytes, stream);
    scatter_kernel<<<sblocks, 256, 0, stream>>>(h1, eidx, flag, aggr, E);
    linear_relu_kernel<false, true><<<GRID2, 256, 0, stream>>>(
        h1, aggr, W2_rel, W2_root, b2, nullptr, part, N);

    // ---- head ----
    final_kernel<<<1, 64, 0, stream>>>(part, GRID2, Wc, bc, out, 1.0f / (float)N);
}

// Round 2
// 904.871 us; speedup vs baseline: 2.9944x; 2.9944x over previous
//
#include <hip/hip_runtime.h>

#define D 64

// ---------------------------------------------------------------------------
// Detect whether edge_index is stored as int64 (odd int32 words all zero,
// since node ids < 2^31) or int32. Writes 1 (int64) / 0 (int32) to *flag.
// ---------------------------------------------------------------------------
__global__ void detect_kernel(const void* __restrict__ e, int* __restrict__ flag) {
    if (threadIdx.x == 0 && blockIdx.x == 0) {
        const int* p = (const int*)e;
        int is64 = 1;
        for (int i = 1; i < 64; i += 2) {
            if (p[i] != 0) { is64 = 0; break; }
        }
        *flag = is64;
    }
}

__device__ __forceinline__ void load_edge(const void* __restrict__ eidx, int is64,
                                          int e, int nE, int& src, int& dst) {
    if (is64) {
        const long long* p = (const long long*)eidx;
        src = (int)p[e];
        dst = (int)p[nE + e];
    } else {
        const int* p = (const int*)eidx;
        src = p[e];
        dst = p[nE + e];
    }
}

// ---------------------------------------------------------------------------
// Counting sort of edges by dst: histogram -> exclusive scan -> position scatter
// ---------------------------------------------------------------------------
__global__ __launch_bounds__(256) void hist_kernel(
    const void* __restrict__ eidx, const int* __restrict__ flag,
    int* __restrict__ count, int nE)
{
    const int is64 = *flag;
    int e = blockIdx.x * 256 + threadIdx.x;
    if (e >= nE) return;
    int src, dst;
    load_edge(eidx, is64, e, nE, src, dst);
    atomicAdd(&count[dst], 1);
}

// per-block exclusive scan of count -> offs, block totals -> bsum
__global__ __launch_bounds__(256) void scan1_kernel(
    const int* __restrict__ count, int* __restrict__ offs,
    int* __restrict__ bsum, int N)
{
    __shared__ int tmp[256];
    const int tid = threadIdx.x;
    const int i = blockIdx.x * 256 + tid;
    int v = (i < N) ? count[i] : 0;
    tmp[tid] = v;
    __syncthreads();
#pragma unroll
    for (int off = 1; off < 256; off <<= 1) {
        int t = (tid >= off) ? tmp[tid - off] : 0;
        __syncthreads();
        tmp[tid] += t;
        __syncthreads();
    }
    int incl = tmp[tid];
    if (i < N) offs[i] = incl - v;          // exclusive
    if (tid == 255) bsum[blockIdx.x] = incl; // block total
}

// single-block exclusive scan of block sums (supports up to 1024 blocks)
__global__ __launch_bounds__(1024) void scan2_kernel(int* __restrict__ bsum, int nblk)
{
    __shared__ int tmp[1024];
    const int tid = threadIdx.x;
    int v = (tid < nblk) ? bsum[tid] : 0;
    tmp[tid] = v;
    __syncthreads();
#pragma unroll
    for (int off = 1; off < 1024; off <<= 1) {
        int t = (tid >= off) ? tmp[tid - off] : 0;
        __syncthreads();
        tmp[tid] += t;
        __syncthreads();
    }
    if (tid < nblk) bsum[tid] = tmp[tid] - v; // exclusive
}

// add block offsets; also produce cursor copy and offs[N] = E
__global__ __launch_bounds__(256) void scan3_kernel(
    int* __restrict__ offs, const int* __restrict__ bsum,
    int* __restrict__ cursor, int N, int E)
{
    const int i = blockIdx.x * 256 + threadIdx.x;
    if (i < N) {
        int v = offs[i] + bsum[blockIdx.x];
        offs[i] = v;
        cursor[i] = v;
    }
    if (i == 0) offs[N] = E;
}

__global__ __launch_bounds__(256) void scatterpos_kernel(
    const void* __restrict__ eidx, const int* __restrict__ flag,
    int* __restrict__ cursor, int* __restrict__ ssrc, int nE)
{
    const int is64 = *flag;
    int e = blockIdx.x * 256 + threadIdx.x;
    if (e >= nE) return;
    int src, dst;
    load_edge(eidx, is64, e, nE, src, dst);
    int pos = atomicAdd(&cursor[dst], 1);
    ssrc[pos] = src;
}

// ---------------------------------------------------------------------------
// Segmented gather-sum: aggr[n] = sum over sorted in-edges of feat[src].
// 16 lanes per node (float4 chunks), 16 nodes per block. No f32 atomics.
// ---------------------------------------------------------------------------
__global__ __launch_bounds__(256) void gather_aggr_kernel(
    const float* __restrict__ feat, const int* __restrict__ ssrc,
    const int* __restrict__ offs, float* __restrict__ aggr, int N)
{
    const int g = threadIdx.x >> 4;   // node group within block
    const int c = threadIdx.x & 15;   // float4 chunk
    const int n = blockIdx.x * 16 + g;
    if (n >= N) return;
    const int e0 = offs[n], e1 = offs[n + 1];
    float4 acc = make_float4(0.f, 0.f, 0.f, 0.f);
    for (int e = e0; e < e1; ++e) {
        int s = ssrc[e];
        float4 v = *(const float4*)(feat + (long long)s * D + c * 4);
        acc.x += v.x; acc.y += v.y; acc.z += v.z; acc.w += v.w;
    }
    *(float4*)(aggr + (long long)n * D + c * 4) = acc;
}

// ---------------------------------------------------------------------------
// Fused linear: out[i][d] = relu( aggr[i]@Wrel + in[i]@Wroot + b )[d]
// One wave per row; lane d holds columns d of both weights in registers.
// ---------------------------------------------------------------------------
template <bool WRITE_OUT, bool WRITE_PART>
__global__ __launch_bounds__(256) void linear_relu_kernel(
    const float* __restrict__ in, const float* __restrict__ aggr,
    const float* __restrict__ Wrel, const float* __restrict__ Wroot,
    const float* __restrict__ bias,
    float* __restrict__ out, float* __restrict__ part, int N)
{
    const int lane = threadIdx.x & 63;
    const int wid  = threadIdx.x >> 6;

    float wrel[D], wroot[D];
#pragma unroll
    for (int k = 0; k < D; ++k) {
        wrel[k]  = Wrel[k * D + lane];
        wroot[k] = Wroot[k * D + lane];
    }
    const float bv = bias[lane];

    float csum = 0.f;
    const long long stride = (long long)gridDim.x * 4;
    for (long long row = (long long)blockIdx.x * 4 + wid; row < N; row += stride) {
        const float* rin = in   + row * D;
        const float* rag = aggr + row * D;
        float acc = bv;
#pragma unroll
        for (int k4 = 0; k4 < D / 4; ++k4) {
            float4 a = *(const float4*)(rin + 4 * k4);
            float4 g = *(const float4*)(rag + 4 * k4);
            acc += a.x * wroot[4 * k4 + 0] + a.y * wroot[4 * k4 + 1]
                 + a.z * wroot[4 * k4 + 2] + a.w * wroot[4 * k4 + 3];
            acc += g.x * wrel[4 * k4 + 0] + g.y * wrel[4 * k4 + 1]
                 + g.z * wrel[4 * k4 + 2] + g.w * wrel[4 * k4 + 3];
        }
        acc = fmaxf(acc, 0.f);
        if (WRITE_OUT) out[row * D + lane] = acc;
        if (WRITE_PART) csum += acc;
    }

    if (WRITE_PART) {
        __shared__ float red[4][D];
        red[wid][lane] = csum;
        __syncthreads();
        if (threadIdx.x < D) {
            float s = red[0][threadIdx.x] + red[1][threadIdx.x]
                    + red[2][threadIdx.x] + red[3][threadIdx.x];
            part[(long long)blockIdx.x * D + threadIdx.x] = s;
        }
    }
}

// ---------------------------------------------------------------------------
// Final: colsum -> mean -> [64] @ Wc[64,2] + bc -> out[2]
// ---------------------------------------------------------------------------
__global__ void final_kernel(const float* __restrict__ part, int nPart,
                             const float* __restrict__ Wc, const float* __restrict__ bc,
                             float* __restrict__ out, float invN)
{
    const int lane = threadIdx.x;  // 64 threads
    float s = 0.f;
    for (int b = 0; b < nPart; ++b) s += part[(long long)b * D + lane];
    float m  = s * invN;
    float o0 = m * Wc[lane * 2 + 0];
    float o1 = m * Wc[lane * 2 + 1];
#pragma unroll
    for (int off = 32; off > 0; off >>= 1) {
        o0 += __shfl_down(o0, off);
        o1 += __shfl_down(o1, off);
    }
    if (lane == 0) {
        out[0] = o0 + bc[0];
        out[1] = o1 + bc[1];
    }
}

extern "C" void kernel_launch(void* const* d_in, const int* in_sizes, int n_in,
                              void* d_out, int out_size, void* d_ws, size_t ws_size,
                              hipStream_t stream)
{
    const float* x       = (const float*)d_in[0];
    const void*  eidx    = d_in[1];
    const float* W1_rel  = (const float*)d_in[2];
    const float* W1_root = (const float*)d_in[3];
    const float* b1      = (const float*)d_in[4];
    const float* W2_rel  = (const float*)d_in[5];
    const float* W2_root = (const float*)d_in[6];
    const float* b2      = (const float*)d_in[7];
    const float* Wc      = (const float*)d_in[8];
    const float* bc      = (const float*)d_in[9];
    float* out = (float*)d_out;

    const int N = in_sizes[0] / D;
    const int E = in_sizes[1] / 2;
    const int GRID2 = 1024;

    auto align256 = [](size_t v) { return (v + 255) & ~(size_t)255; };

    char* p = (char*)d_ws;
    const size_t featBytes = align256((size_t)N * D * sizeof(float));
    float* aggr   = (float*)p; p += featBytes;
    float* h1     = (float*)p; p += featBytes;
    float* part   = (float*)p; p += align256((size_t)GRID2 * D * sizeof(float));
    int*   count  = (int*)p;   p += align256((size_t)N * sizeof(int));
    int*   cursor = (int*)p;   p += align256((size_t)N * sizeof(int));
    int*   offs   = (int*)p;   p += align256(((size_t)N + 1) * sizeof(int));
    int*   bsum   = (int*)p;   p += align256((size_t)1024 * sizeof(int));
    int*   ssrc   = (int*)p;   p += align256((size_t)E * sizeof(int));
    int*   flag   = (int*)p;

    const int eblocks = (E + 255) / 256;
    const int nblk    = (N + 255) / 256;   // scan blocks (must be <= 1024)

    // ---- sort edges by dst (once, reused by both layers) ----
    detect_kernel<<<1, 64, 0, stream>>>(eidx, flag);
    hipMemsetAsync(count, 0, (size_t)N * sizeof(int), stream);
    hist_kernel<<<eblocks, 256, 0, stream>>>(eidx, flag, count, E);
    scan1_kernel<<<nblk, 256, 0, stream>>>(count, offs, bsum, N);
    scan2_kernel<<<1, 1024, 0, stream>>>(bsum, nblk);
    scan3_kernel<<<nblk, 256, 0, stream>>>(offs, bsum, cursor, N, E);
    scatterpos_kernel<<<eblocks, 256, 0, stream>>>(eidx, flag, cursor, ssrc, E);

    const int ablocks = (N + 15) / 16;

    // ---- layer 1 ----
    gather_aggr_kernel<<<ablocks, 256, 0, stream>>>(x, ssrc, offs, aggr, N);
    linear_relu_kernel<true, false><<<2048, 256, 0, stream>>>(
        x, aggr, W1_rel, W1_root, b1, h1, nullptr, N);

    // ---- layer 2 ----
    gather_aggr_kernel<<<ablocks, 256, 0, stream>>>(h1, ssrc, offs, aggr, N);
    linear_relu_kernel<false, true><<<GRID2, 256, 0, stream>>>(
        h1, aggr, W2_rel, W2_root, b2, nullptr, part, N);

    // ---- head ----
    final_kernel<<<1, 64, 0, stream>>>(part, GRID2, Wc, bc, out, 1.0f / (float)N);
}

// Round 3
// 676.800 us; speedup vs baseline: 4.0034x; 1.3370x over previous
//
#include <hip/hip_runtime.h>

#define D 64

// ---------------------------------------------------------------------------
// Detect whether edge_index is stored as int64 (odd int32 words all zero,
// since node ids < 2^31) or int32. Writes 1 (int64) / 0 (int32) to *flag.
// ---------------------------------------------------------------------------
__global__ void detect_kernel(const void* __restrict__ e, int* __restrict__ flag) {
    if (threadIdx.x == 0 && blockIdx.x == 0) {
        const int* p = (const int*)e;
        int is64 = 1;
        for (int i = 1; i < 64; i += 2) {
            if (p[i] != 0) { is64 = 0; break; }
        }
        *flag = is64;
    }
}

__device__ __forceinline__ void load_edge(const void* __restrict__ eidx, int is64,
                                          int e, int nE, int& src, int& dst) {
    if (is64) {
        const long long* p = (const long long*)eidx;
        src = (int)p[e];
        dst = (int)p[nE + e];
    } else {
        const int* p = (const int*)eidx;
        src = p[e];
        dst = p[nE + e];
    }
}

// ---------------------------------------------------------------------------
// Counting sort of edges by dst: histogram -> exclusive scan -> position scatter
// ---------------------------------------------------------------------------
__global__ __launch_bounds__(256) void hist_kernel(
    const void* __restrict__ eidx, const int* __restrict__ flag,
    int* __restrict__ count, int nE)
{
    const int is64 = *flag;
    int e = blockIdx.x * 256 + threadIdx.x;
    if (e >= nE) return;
    int src, dst;
    load_edge(eidx, is64, e, nE, src, dst);
    atomicAdd(&count[dst], 1);
}

// per-block exclusive scan of count -> offs, block totals -> bsum
__global__ __launch_bounds__(256) void scan1_kernel(
    const int* __restrict__ count, int* __restrict__ offs,
    int* __restrict__ bsum, int N)
{
    __shared__ int tmp[256];
    const int tid = threadIdx.x;
    const int i = blockIdx.x * 256 + tid;
    int v = (i < N) ? count[i] : 0;
    tmp[tid] = v;
    __syncthreads();
#pragma unroll
    for (int off = 1; off < 256; off <<= 1) {
        int t = (tid >= off) ? tmp[tid - off] : 0;
        __syncthreads();
        tmp[tid] += t;
        __syncthreads();
    }
    int incl = tmp[tid];
    if (i < N) offs[i] = incl - v;          // exclusive
    if (tid == 255) bsum[blockIdx.x] = incl; // block total
}

// single-block exclusive scan of block sums (supports up to 1024 blocks)
__global__ __launch_bounds__(1024) void scan2_kernel(int* __restrict__ bsum, int nblk)
{
    __shared__ int tmp[1024];
    const int tid = threadIdx.x;
    int v = (tid < nblk) ? bsum[tid] : 0;
    tmp[tid] = v;
    __syncthreads();
#pragma unroll
    for (int off = 1; off < 1024; off <<= 1) {
        int t = (tid >= off) ? tmp[tid - off] : 0;
        __syncthreads();
        tmp[tid] += t;
        __syncthreads();
    }
    if (tid < nblk) bsum[tid] = tmp[tid] - v; // exclusive
}

// add block offsets; also produce cursor copy and offs[N] = E
__global__ __launch_bounds__(256) void scan3_kernel(
    int* __restrict__ offs, const int* __restrict__ bsum,
    int* __restrict__ cursor, int N, int E)
{
    const int i = blockIdx.x * 256 + threadIdx.x;
    if (i < N) {
        int v = offs[i] + bsum[blockIdx.x];
        offs[i] = v;
        cursor[i] = v;
    }
    if (i == 0) offs[N] = E;
}

__global__ __launch_bounds__(256) void scatterpos_kernel(
    const void* __restrict__ eidx, const int* __restrict__ flag,
    int* __restrict__ cursor, int* __restrict__ ssrc, int nE)
{
    const int is64 = *flag;
    int e = blockIdx.x * 256 + threadIdx.x;
    if (e >= nE) return;
    int src, dst;
    load_edge(eidx, is64, e, nE, src, dst);
    int pos = atomicAdd(&cursor[dst], 1);
    ssrc[pos] = src;
}

// ---------------------------------------------------------------------------
// Segmented gather-sum: aggr[n] = sum over sorted in-edges of feat[src].
// 16 lanes per node (float4 chunks), 16 nodes per block. No f32 atomics.
// ---------------------------------------------------------------------------
__global__ __launch_bounds__(256) void gather_aggr_kernel(
    const float* __restrict__ feat, const int* __restrict__ ssrc,
    const int* __restrict__ offs, float* __restrict__ aggr, int N)
{
    const int g = threadIdx.x >> 4;   // node group within block
    const int c = threadIdx.x & 15;   // float4 chunk
    const int n = blockIdx.x * 16 + g;
    if (n >= N) return;
    const int e0 = offs[n], e1 = offs[n + 1];
    float4 acc = make_float4(0.f, 0.f, 0.f, 0.f);
    for (int e = e0; e < e1; ++e) {
        int s = ssrc[e];
        float4 v = *(const float4*)(feat + (long long)s * D + c * 4);
        acc.x += v.x; acc.y += v.y; acc.z += v.z; acc.w += v.w;
    }
    *(float4*)(aggr + (long long)n * D + c * 4) = acc;
}

// ---------------------------------------------------------------------------
// Fused linear: out[i][d] = relu( aggr[i]@Wrel + in[i]@Wroot + b )[d]
// One wave per row; lane d holds columns d of both weights in registers.
// WRITE_PART: per-block column sums are atomically added into acc[64].
// ---------------------------------------------------------------------------
template <bool WRITE_OUT, bool WRITE_PART>
__global__ __launch_bounds__(256) void linear_relu_kernel(
    const float* __restrict__ in, const float* __restrict__ aggr,
    const float* __restrict__ Wrel, const float* __restrict__ Wroot,
    const float* __restrict__ bias,
    float* __restrict__ out, float* __restrict__ acc_out, int N)
{
    const int lane = threadIdx.x & 63;
    const int wid  = threadIdx.x >> 6;

    float wrel[D], wroot[D];
#pragma unroll
    for (int k = 0; k < D; ++k) {
        wrel[k]  = Wrel[k * D + lane];
        wroot[k] = Wroot[k * D + lane];
    }
    const float bv = bias[lane];

    float csum = 0.f;
    const long long stride = (long long)gridDim.x * 4;
    for (long long row = (long long)blockIdx.x * 4 + wid; row < N; row += stride) {
        const float* rin = in   + row * D;
        const float* rag = aggr + row * D;
        float acc = bv;
#pragma unroll
        for (int k4 = 0; k4 < D / 4; ++k4) {
            float4 a = *(const float4*)(rin + 4 * k4);
            float4 g = *(const float4*)(rag + 4 * k4);
            acc += a.x * wroot[4 * k4 + 0] + a.y * wroot[4 * k4 + 1]
                 + a.z * wroot[4 * k4 + 2] + a.w * wroot[4 * k4 + 3];
            acc += g.x * wrel[4 * k4 + 0] + g.y * wrel[4 * k4 + 1]
                 + g.z * wrel[4 * k4 + 2] + g.w * wrel[4 * k4 + 3];
        }
        acc = fmaxf(acc, 0.f);
        if (WRITE_OUT) out[row * D + lane] = acc;
        if (WRITE_PART) csum += acc;
    }

    if (WRITE_PART) {
        __shared__ float red[4][D];
        red[wid][lane] = csum;
        __syncthreads();
        if (threadIdx.x < D) {
            float s = red[0][threadIdx.x] + red[1][threadIdx.x]
                    + red[2][threadIdx.x] + red[3][threadIdx.x];
            unsafeAtomicAdd(&acc_out[threadIdx.x], s);
        }
    }
}

// ---------------------------------------------------------------------------
// Final: acc[64] -> mean -> [64] @ Wc[64,2] + bc -> out[2]
// ---------------------------------------------------------------------------
__global__ void final_kernel(const float* __restrict__ acc,
                             const float* __restrict__ Wc, const float* __restrict__ bc,
                             float* __restrict__ out, float invN)
{
    const int lane = threadIdx.x;  // 64 threads
    float m  = acc[lane] * invN;
    float o0 = m * Wc[lane * 2 + 0];
    float o1 = m * Wc[lane * 2 + 1];
#pragma unroll
    for (int off = 32; off > 0; off >>= 1) {
        o0 += __shfl_down(o0, off);
        o1 += __shfl_down(o1, off);
    }
    if (lane == 0) {
        out[0] = o0 + bc[0];
        out[1] = o1 + bc[1];
    }
}

extern "C" void kernel_launch(void* const* d_in, const int* in_sizes, int n_in,
                              void* d_out, int out_size, void* d_ws, size_t ws_size,
                              hipStream_t stream)
{
    const float* x       = (const float*)d_in[0];
    const void*  eidx    = d_in[1];
    const float* W1_rel  = (const float*)d_in[2];
    const float* W1_root = (const float*)d_in[3];
    const float* b1      = (const float*)d_in[4];
    const float* W2_rel  = (const float*)d_in[5];
    const float* W2_root = (const float*)d_in[6];
    const float* b2      = (const float*)d_in[7];
    const float* Wc      = (const float*)d_in[8];
    const float* bc      = (const float*)d_in[9];
    float* out = (float*)d_out;

    const int N = in_sizes[0] / D;
    const int E = in_sizes[1] / 2;

    auto align256 = [](size_t v) { return (v + 255) & ~(size_t)255; };

    char* p = (char*)d_ws;
    const size_t featBytes = align256((size_t)N * D * sizeof(float));
    float* aggr   = (float*)p; p += featBytes;
    float* h1     = (float*)p; p += featBytes;
    float* acc    = (float*)p; p += align256((size_t)D * sizeof(float));
    int*   count  = (int*)p;   p += align256((size_t)N * sizeof(int));
    int*   cursor = (int*)p;   p += align256((size_t)N * sizeof(int));
    int*   offs   = (int*)p;   p += align256(((size_t)N + 1) * sizeof(int));
    int*   bsum   = (int*)p;   p += align256((size_t)1024 * sizeof(int));
    int*   ssrc   = (int*)p;   p += align256((size_t)E * sizeof(int));
    int*   flag   = (int*)p;

    const int eblocks = (E + 255) / 256;
    const int nblk    = (N + 255) / 256;   // scan blocks (must be <= 1024)

    // ---- sort edges by dst (once, reused by both layers) ----
    detect_kernel<<<1, 64, 0, stream>>>(eidx, flag);
    hipMemsetAsync(count, 0, (size_t)N * sizeof(int), stream);
    hipMemsetAsync(acc, 0, (size_t)D * sizeof(float), stream);
    hist_kernel<<<eblocks, 256, 0, stream>>>(eidx, flag, count, E);
    scan1_kernel<<<nblk, 256, 0, stream>>>(count, offs, bsum, N);
    scan2_kernel<<<1, 1024, 0, stream>>>(bsum, nblk);
    scan3_kernel<<<nblk, 256, 0, stream>>>(offs, bsum, cursor, N, E);
    scatterpos_kernel<<<eblocks, 256, 0, stream>>>(eidx, flag, cursor, ssrc, E);

    const int ablocks = (N + 15) / 16;

    // ---- layer 1 ----
    gather_aggr_kernel<<<ablocks, 256, 0, stream>>>(x, ssrc, offs, aggr, N);
    linear_relu_kernel<true, false><<<2048, 256, 0, stream>>>(
        x, aggr, W1_rel, W1_root, b1, h1, nullptr, N);

    // ---- layer 2 ----
    gather_aggr_kernel<<<ablocks, 256, 0, stream>>>(h1, ssrc, offs, aggr, N);
    linear_relu_kernel<false, true><<<1024, 256, 0, stream>>>(
        h1, aggr, W2_rel, W2_root, b2, nullptr, acc, N);

    // ---- head ----
    final_kernel<<<1, 64, 0, stream>>>(acc, Wc, bc, out, 1.0f / (float)N);
}